// Round 4
// baseline (1614.752 us; speedup 1.0000x reference)
//
#include <hip/hip_runtime.h>
#include <hip/hip_fp16.h>

typedef _Float16 f16;
typedef _Float16 f16x8 __attribute__((ext_vector_type(8)));
typedef float f32x4 __attribute__((ext_vector_type(4)));

#define B_ 256
#define N_ 2048
#define D_ 256

// ---------------------------------------------------------------------------
// prep_w: W[0][d][k] (k<256, feature half) -> fp16 HI plane only, laid out in
// MFMA B-fragment order [ks(8)][ct(16)][lane(64)][j(8)]:
//   ct = d>>4, lane = (d&15) | (((k>>3)&3)<<4), ks = k>>5, j = k&7
// Frag (ks,ct) occupies a contiguous 1 KiB block -> ds_read_b128 at
// base(ks) + imm(ct*1024), lane-contiguous 16B => conflict-free.
// ---------------------------------------------------------------------------
__global__ void prep_w(const float* __restrict__ W, f16* __restrict__ wbuf) {
    int idx = blockIdx.x * 256 + threadIdx.x;   // 65536 total
    int d = idx >> 8, k = idx & 255;
    float w = W[d * 512 + k];
    int ct   = d >> 4;
    int lane = (d & 15) | (((k >> 3) & 3) << 4);
    int ks   = k >> 5;
    int j    = k & 7;
    wbuf[(((ks * 16 + ct) * 64) + lane) * 8 + j] = (f16)w;
}

// ---------------------------------------------------------------------------
// prep_c: c[b][d] = sum_e W[0][d][256+e] * h[b][e]   (fp32 exact, tiny)
// ---------------------------------------------------------------------------
__global__ void prep_c(const float* __restrict__ W, const float* __restrict__ h,
                       float* __restrict__ c) {
    __shared__ float hs[256];
    int b = blockIdx.x, d = threadIdx.x;
    hs[d] = h[b * 256 + d];
    __syncthreads();
    const float4* w4 = (const float4*)(W + d * 512 + 256);
    const float4* h4 = (const float4*)hs;
    float acc = 0.f;
#pragma unroll 8
    for (int e = 0; e < 64; ++e) {
        float4 a = w4[e], bb = h4[e];
        acc += a.x * bb.x + a.y * bb.y + a.z * bb.z + a.w * bb.w;
    }
    c[b * 256 + d] = acc;
}

// ---------------------------------------------------------------------------
// main_gemm: barrier-free row-parallel design.
//   grid = 256 blocks (block b == batch b), 1024 threads = 16 waves.
//   Wave w, step wt: rows b*2048 + wt*256 + w*16 + (l&15); all 256 d-cols.
//   A (feature): global -> regs, fp32, split to f16 hi+lo on the fly.
//   B (W hi-plane): LDS-resident (128 KiB), read once per (ks,ct) frag,
//   each frag feeds 2 MFMAs (hi,lo) -> 2-pass split precision
//   f_hi*W_hi + f_lo*W_hi (dropped term f*W_lo ~ 2^-11, same scale as before).
//   acc[16] (64 VGPR); no __syncthreads after init; 4 waves/SIMD.
// ---------------------------------------------------------------------------
__global__ __launch_bounds__(1024, 4)
void main_gemm(const float* __restrict__ feat, const f16* __restrict__ wbuf,
               const float* __restrict__ cb, const float* __restrict__ vvec,
               float* __restrict__ scores) {
    __shared__ f16 wlds[65536];   // 128 KiB

    const int tid = threadIdx.x;
    const int w = tid >> 6;       // wave 0..15
    const int l = tid & 63;
    const int g = l >> 4;         // 0..3
    const int lr = l & 15;        // row-within-16 / d-lane
    const int b = blockIdx.x;     // batch

    // ---- W hi-plane -> LDS (coalesced 128 KiB copy) ----
    {
        const uint4* ws = (const uint4*)wbuf;
        uint4* wd = (uint4*)wlds;
#pragma unroll
        for (int i = 0; i < 8; ++i) wd[i * 1024 + tid] = ws[i * 1024 + tid];
    }
    __syncthreads();   // only barrier in the kernel

    // per-lane feature base: row b*2048 + w*16 + lr, k-offset g*8
    const float* fbase = feat + ((size_t)b * 2048 + w * 16 + lr) * 256 + g * 8;

    for (int wt = 0; wt < 8; ++wt) {
        const float* fp = fbase + wt * (256 * 256);
        f32x4 acc[16] = {};

        float4 a0 = *(const float4*)(fp);
        float4 a1 = *(const float4*)(fp + 4);
#pragma unroll
        for (int ks = 0; ks < 8; ++ks) {
            float4 n0, n1;
            if (ks < 7) {
                n0 = *(const float4*)(fp + (ks + 1) * 32);
                n1 = *(const float4*)(fp + (ks + 1) * 32 + 4);
            }
            // split current 8 fp32 into f16 hi + lo
            f16x8 ahi, alo;
            ahi[0] = (f16)a0.x; ahi[1] = (f16)a0.y; ahi[2] = (f16)a0.z; ahi[3] = (f16)a0.w;
            ahi[4] = (f16)a1.x; ahi[5] = (f16)a1.y; ahi[6] = (f16)a1.z; ahi[7] = (f16)a1.w;
            alo[0] = (f16)(a0.x - (float)ahi[0]);
            alo[1] = (f16)(a0.y - (float)ahi[1]);
            alo[2] = (f16)(a0.z - (float)ahi[2]);
            alo[3] = (f16)(a0.w - (float)ahi[3]);
            alo[4] = (f16)(a1.x - (float)ahi[4]);
            alo[5] = (f16)(a1.y - (float)ahi[5]);
            alo[6] = (f16)(a1.z - (float)ahi[6]);
            alo[7] = (f16)(a1.w - (float)ahi[7]);

            const f16x8* wk = (const f16x8*)(wlds + ks * 8192 + l * 8);
#pragma unroll
            for (int ct = 0; ct < 16; ++ct) {
                f16x8 bw = wk[ct * 64];   // imm offset ct*1024 B, conflict-free
                acc[ct] = __builtin_amdgcn_mfma_f32_16x16x32_f16(ahi, bw, acc[ct], 0, 0, 0);
                acc[ct] = __builtin_amdgcn_mfma_f32_16x16x32_f16(alo, bw, acc[ct], 0, 0, 0);
            }
            if (ks < 7) { a0 = n0; a1 = n1; }
        }

        // ---- epilogue: +c, tanh, *v, sum over d ----
        // acc[ct][r] = inner[row = g*4+r][d = ct*16+lr]
        float s0 = 0.f, s1 = 0.f, s2 = 0.f, s3 = 0.f;
#pragma unroll
        for (int ct = 0; ct < 16; ++ct) {
            float c  = cb[b * 256 + ct * 16 + lr];
            float vv = vvec[ct * 16 + lr];
            float x0 = acc[ct][0] + c;
            float x1 = acc[ct][1] + c;
            float x2 = acc[ct][2] + c;
            float x3 = acc[ct][3] + c;
            float t0 = 1.f - __fdividef(2.f, __expf(2.f * x0) + 1.f);
            float t1 = 1.f - __fdividef(2.f, __expf(2.f * x1) + 1.f);
            float t2 = 1.f - __fdividef(2.f, __expf(2.f * x2) + 1.f);
            float t3 = 1.f - __fdividef(2.f, __expf(2.f * x3) + 1.f);
            s0 += vv * t0; s1 += vv * t1; s2 += vv * t2; s3 += vv * t3;
        }
        // reduce over the 16 d-lanes (lr)
#pragma unroll
        for (int m = 1; m < 16; m <<= 1) {
            s0 += __shfl_xor(s0, m, 64);
            s1 += __shfl_xor(s1, m, 64);
            s2 += __shfl_xor(s2, m, 64);
            s3 += __shfl_xor(s3, m, 64);
        }
        if (lr == 0) {
            float4 o = {s0, s1, s2, s3};
            *(float4*)(scores + (size_t)b * 2048 + wt * 256 + w * 16 + g * 4) = o;
        }
    }
}

// ---------------------------------------------------------------------------
// softmax over n (2048) per b; out[b*2048+n]
// ---------------------------------------------------------------------------
__global__ void softmax_k(const float* __restrict__ scores, float* __restrict__ out) {
    __shared__ float red[16];
    int b = blockIdx.x, tid = threadIdx.x;  // 256 threads
    const float4* s4 = (const float4*)(scores + b * 2048);
    float4 x0 = s4[tid], x1 = s4[tid + 256];
    float m = fmaxf(fmaxf(fmaxf(x0.x, x0.y), fmaxf(x0.z, x0.w)),
                    fmaxf(fmaxf(x1.x, x1.y), fmaxf(x1.z, x1.w)));
#pragma unroll
    for (int d = 1; d < 64; d <<= 1) m = fmaxf(m, __shfl_xor(m, d, 64));
    if ((tid & 63) == 0) red[tid >> 6] = m;
    __syncthreads();
    m = fmaxf(fmaxf(red[0], red[1]), fmaxf(red[2], red[3]));
    float e0 = __expf(x0.x - m), e1 = __expf(x0.y - m), e2 = __expf(x0.z - m), e3 = __expf(x0.w - m);
    float e4 = __expf(x1.x - m), e5 = __expf(x1.y - m), e6 = __expf(x1.z - m), e7 = __expf(x1.w - m);
    float sum = ((e0 + e1) + (e2 + e3)) + ((e4 + e5) + (e6 + e7));
#pragma unroll
    for (int d = 1; d < 64; d <<= 1) sum += __shfl_xor(sum, d, 64);
    if ((tid & 63) == 0) red[8 + (tid >> 6)] = sum;
    __syncthreads();
    sum = (red[8] + red[9]) + (red[10] + red[11]);
    float inv = __fdividef(1.f, sum);
    float4 o0 = {e0 * inv, e1 * inv, e2 * inv, e3 * inv};
    float4 o1 = {e4 * inv, e5 * inv, e6 * inv, e7 * inv};
    float4* o4 = (float4*)(out + b * 2048);
    o4[tid] = o0;
    o4[tid + 256] = o1;
}

// ---------------------------------------------------------------------------
extern "C" void kernel_launch(void* const* d_in, const int* in_sizes, int n_in,
                              void* d_out, int out_size, void* d_ws, size_t ws_size,
                              hipStream_t stream) {
    const float* feat = (const float*)d_in[0];   // [256,2048,256]
    const float* h    = (const float*)d_in[1];   // [256,256]
    const float* v    = (const float*)d_in[2];   // [256]
    const float* W    = (const float*)d_in[3];   // [256,512]
    float* out = (float*)d_out;                  // [256,1,2048]

    f16*   wbuf   = (f16*)d_ws;                          // 131072 B (hi plane)
    float* cbuf   = (float*)((char*)d_ws + 262144);      // 262144 B
    float* scores = (float*)((char*)d_ws + 524288);      // 2 MiB

    prep_w<<<256, 256, 0, stream>>>(W, wbuf);
    prep_c<<<256, 256, 0, stream>>>(W, h, cbuf);
    main_gemm<<<256, 1024, 0, stream>>>(feat, wbuf, cbuf, v, scores);
    softmax_k<<<256, 256, 0, stream>>>(scores, out);
}

// Round 5
// 242.293 us; speedup vs baseline: 6.6645x; 6.6645x over previous
//
#include <hip/hip_runtime.h>
#include <hip/hip_fp16.h>

typedef _Float16 f16;
typedef _Float16 f16x8 __attribute__((ext_vector_type(8)));
typedef float f32x4 __attribute__((ext_vector_type(4)));

#define TPW 32   // tiles (of 64 rows) per block; block b == batch b

// ---------------------------------------------------------------------------
// prep_w: W[0][d][k] (k<256, feature half) -> fp16 HI plane, MFMA B-frag order
// [ks(8)][ct(16)][lane(64)][j(8)]: ct=d>>4, lane=(d&15)|(((k>>3)&3)<<4),
// ks=k>>5, j=k&7. Frag (ks,ct) = contiguous 1 KiB.
// ---------------------------------------------------------------------------
__global__ void prep_w(const float* __restrict__ W, f16* __restrict__ wbuf) {
    int idx = blockIdx.x * 256 + threadIdx.x;   // 65536 total
    int d = idx >> 8, k = idx & 255;
    float w = W[d * 512 + k];
    int ct   = d >> 4;
    int lane = (d & 15) | (((k >> 3) & 3) << 4);
    int ks   = k >> 5;
    int j    = k & 7;
    wbuf[(((ks * 16 + ct) * 64) + lane) * 8 + j] = (f16)w;
}

// ---------------------------------------------------------------------------
// prep_c: c[b][d] = sum_e W[0][d][256+e] * h[b][e]   (fp32 exact, tiny)
// ---------------------------------------------------------------------------
__global__ void prep_c(const float* __restrict__ W, const float* __restrict__ h,
                       float* __restrict__ c) {
    __shared__ float hs[256];
    int b = blockIdx.x, d = threadIdx.x;
    hs[d] = h[b * 256 + d];
    __syncthreads();
    const float4* w4 = (const float4*)(W + d * 512 + 256);
    const float4* h4 = (const float4*)hs;
    float acc = 0.f;
#pragma unroll 8
    for (int e = 0; e < 64; ++e) {
        float4 a = w4[e], bb = h4[e];
        acc += a.x * bb.x + a.y * bb.y + a.z * bb.z + a.w * bb.w;
    }
    c[b * 256 + d] = acc;
}

// ---------------------------------------------------------------------------
// main_gemm: A (feature) staged as RAW FP32 to LDS via global_load_lds
// (linear dest, swizzle folded into the per-lane GLOBAL source address:
// L[x] = T[x ^ ((row&7)<<4)], row = x>>10). hi/lo fp16 split happens at
// LDS->reg read; 2-pass split precision ahi*Whi + alo*Whi (W hi only).
// 8 waves = 2 row-halves x 4 col-quarters; wave owns 32 rows x 64 cols.
// wf[4][8] (128 VGPR) + acc[2][4] (32) -> ~205 regs, 2 waves/SIMD, no spill.
// One barrier per tile; DMA for t+1 issued right after it.
// ---------------------------------------------------------------------------
__global__ __launch_bounds__(512, 2)
void main_gemm(const float* __restrict__ feat, const f16* __restrict__ wbuf,
               const float* __restrict__ cb, const float* __restrict__ vvec,
               float* __restrict__ psc) {
    __shared__ __align__(16) char lds[131072];   // 2 x 64 KB fp32 A-tiles

    const int tid = threadIdx.x;
    const int w = tid >> 6;       // wave 0..7
    const int l = tid & 63;
    const int g = l >> 4;         // 0..3
    const int lr = l & 15;
    const int wr = w >> 2;        // row-half 0/1
    const int wc = w & 3;         // col-quarter 0..3
    const int b = blockIdx.x;     // batch

    // ---- W-hi fragments for this wave's 64 cols: wf[ct][ks], 128 VGPRs ----
    f16x8 wf[4][8];
    {
        const f16x8* wp = (const f16x8*)wbuf;
#pragma unroll
        for (int ct = 0; ct < 4; ++ct) {
            int ctg = wc * 4 + ct;
#pragma unroll
            for (int ks = 0; ks < 8; ++ks)
                wf[ct][ks] = wp[(ks * 16 + ctg) * 64 + l];
        }
    }
    float c_[4], v_[4];
#pragma unroll
    for (int ct = 0; ct < 4; ++ct) {
        c_[ct] = cb[b * 256 + (wc * 4 + ct) * 16 + lr];
        v_[ct] = vvec[(wc * 4 + ct) * 16 + lr];
    }

    // DMA: thread j, iter i writes LDS bytes [i*8192 + j*16, +16) from global
    // byte i*8192 + sj*16, where sj = j with low-3 bits XORed by wave id.
    const int sj = (tid & ~7) | ((tid ^ w) & 7);
    const char* tbb = (const char*)(feat + (size_t)b * 2048 * 256);

    // ---- prologue: DMA tile 0 into buf0 ----
#pragma unroll
    for (int i = 0; i < 8; ++i)
        __builtin_amdgcn_global_load_lds(
            (const __attribute__((address_space(1))) void*)(tbb + i * 8192 + sj * 16),
            (__attribute__((address_space(3))) void*)(lds + i * 8192 + tid * 16),
            16, 0, 0);

    for (int t = 0; t < TPW; ++t) {
        __syncthreads();   // buf(t&1) staged (vmcnt drained); buf(~t&1) free
        char* P = lds + (t & 1) * 65536;
        char* Q = lds + ((t + 1) & 1) * 65536;
        if (t + 1 < TPW) {
            const char* nb = tbb + (size_t)(t + 1) * 65536;
#pragma unroll
            for (int i = 0; i < 8; ++i)
                __builtin_amdgcn_global_load_lds(
                    (const __attribute__((address_space(1))) void*)(nb + i * 8192 + sj * 16),
                    (__attribute__((address_space(3))) void*)(Q + i * 8192 + tid * 16),
                    16, 0, 0);
        }

        f32x4 acc[2][4] = {};
#pragma unroll
        for (int ks = 0; ks < 8; ++ks) {
#pragma unroll
            for (int rt = 0; rt < 2; ++rt) {
                int row  = wr * 32 + rt * 16 + lr;
                int base = row * 1024 + ks * 128 + g * 32;
                int swz  = (row & 7) << 4;
                f32x4 r0 = *(const f32x4*)(P + (base ^ swz));
                f32x4 r1 = *(const f32x4*)(P + ((base + 16) ^ swz));
                f16x8 ahi, alo;
                ahi[0] = (f16)r0[0]; ahi[1] = (f16)r0[1];
                ahi[2] = (f16)r0[2]; ahi[3] = (f16)r0[3];
                ahi[4] = (f16)r1[0]; ahi[5] = (f16)r1[1];
                ahi[6] = (f16)r1[2]; ahi[7] = (f16)r1[3];
                alo[0] = (f16)(r0[0] - (float)ahi[0]);
                alo[1] = (f16)(r0[1] - (float)ahi[1]);
                alo[2] = (f16)(r0[2] - (float)ahi[2]);
                alo[3] = (f16)(r0[3] - (float)ahi[3]);
                alo[4] = (f16)(r1[0] - (float)ahi[4]);
                alo[5] = (f16)(r1[1] - (float)ahi[5]);
                alo[6] = (f16)(r1[2] - (float)ahi[6]);
                alo[7] = (f16)(r1[3] - (float)ahi[7]);
                acc[rt][0] = __builtin_amdgcn_mfma_f32_16x16x32_f16(ahi, wf[0][ks], acc[rt][0], 0, 0, 0);
                acc[rt][1] = __builtin_amdgcn_mfma_f32_16x16x32_f16(ahi, wf[1][ks], acc[rt][1], 0, 0, 0);
                acc[rt][2] = __builtin_amdgcn_mfma_f32_16x16x32_f16(ahi, wf[2][ks], acc[rt][2], 0, 0, 0);
                acc[rt][3] = __builtin_amdgcn_mfma_f32_16x16x32_f16(ahi, wf[3][ks], acc[rt][3], 0, 0, 0);
                acc[rt][0] = __builtin_amdgcn_mfma_f32_16x16x32_f16(alo, wf[0][ks], acc[rt][0], 0, 0, 0);
                acc[rt][1] = __builtin_amdgcn_mfma_f32_16x16x32_f16(alo, wf[1][ks], acc[rt][1], 0, 0, 0);
                acc[rt][2] = __builtin_amdgcn_mfma_f32_16x16x32_f16(alo, wf[2][ks], acc[rt][2], 0, 0, 0);
                acc[rt][3] = __builtin_amdgcn_mfma_f32_16x16x32_f16(alo, wf[3][ks], acc[rt][3], 0, 0, 0);
            }
        }

        // ---- epilogue: +c, tanh, *v, sum over this wave's 64 cols ----
        // acc[rt][ct][r]: row = wr*32+rt*16+g*4+r, col = (wc*4+ct)*16+lr
#pragma unroll
        for (int rt = 0; rt < 2; ++rt) {
            float s[4];
#pragma unroll
            for (int r = 0; r < 4; ++r) {
                float a = 0.f;
#pragma unroll
                for (int ct = 0; ct < 4; ++ct) {
                    float x = acc[rt][ct][r] + c_[ct];
                    float tnh = 1.f - __fdividef(2.f, __expf(2.f * x) + 1.f);
                    a += v_[ct] * tnh;
                }
                s[r] = a;
            }
#pragma unroll
            for (int m = 1; m < 16; m <<= 1) {
                s[0] += __shfl_xor(s[0], m, 64);
                s[1] += __shfl_xor(s[1], m, 64);
                s[2] += __shfl_xor(s[2], m, 64);
                s[3] += __shfl_xor(s[3], m, 64);
            }
            if (lr == 0) {
                size_t rowg = (size_t)b * 2048 + t * 64 + wr * 32 + rt * 16 + g * 4;
                psc[(rowg + 0) * 4 + wc] = s[0];
                psc[(rowg + 1) * 4 + wc] = s[1];
                psc[(rowg + 2) * 4 + wc] = s[2];
                psc[(rowg + 3) * 4 + wc] = s[3];
            }
        }
    }
}

// ---------------------------------------------------------------------------
// softmax over n (2048) per b, summing the 4 per-wave partials per row.
// ---------------------------------------------------------------------------
__global__ void softmax_k(const float* __restrict__ psc, float* __restrict__ out) {
    __shared__ float red[16];
    int b = blockIdx.x, tid = threadIdx.x;  // 256 threads
    const float4* pp = (const float4*)(psc + (size_t)b * 2048 * 4);
    float sc[8];
    float m = -3.4e38f;
#pragma unroll
    for (int q = 0; q < 8; ++q) {
        float4 p = pp[q * 256 + tid];
        sc[q] = (p.x + p.y) + (p.z + p.w);
        m = fmaxf(m, sc[q]);
    }
#pragma unroll
    for (int d = 1; d < 64; d <<= 1) m = fmaxf(m, __shfl_xor(m, d, 64));
    if ((tid & 63) == 0) red[tid >> 6] = m;
    __syncthreads();
    m = fmaxf(fmaxf(red[0], red[1]), fmaxf(red[2], red[3]));
    float e[8], sum = 0.f;
#pragma unroll
    for (int q = 0; q < 8; ++q) { e[q] = __expf(sc[q] - m); sum += e[q]; }
#pragma unroll
    for (int d = 1; d < 64; d <<= 1) sum += __shfl_xor(sum, d, 64);
    if ((tid & 63) == 0) red[8 + (tid >> 6)] = sum;
    __syncthreads();
    sum = (red[8] + red[9]) + (red[10] + red[11]);
    float inv = __fdividef(1.f, sum);
#pragma unroll
    for (int q = 0; q < 8; ++q)
        out[(size_t)b * 2048 + q * 256 + tid] = e[q] * inv;
}

// ---------------------------------------------------------------------------
extern "C" void kernel_launch(void* const* d_in, const int* in_sizes, int n_in,
                              void* d_out, int out_size, void* d_ws, size_t ws_size,
                              hipStream_t stream) {
    const float* feat = (const float*)d_in[0];   // [256,2048,256]
    const float* h    = (const float*)d_in[1];   // [256,256]
    const float* v    = (const float*)d_in[2];   // [256]
    const float* W    = (const float*)d_in[3];   // [256,512]
    float* out = (float*)d_out;                  // [256,1,2048]

    f16*   wbuf = (f16*)d_ws;                         // 131072 B (hi plane)
    float* cbuf = (float*)((char*)d_ws + 131072);     // 262144 B
    float* psc  = (float*)((char*)d_ws + 524288);     // 8 MiB partial scores

    prep_w<<<256, 256, 0, stream>>>(W, wbuf);
    prep_c<<<256, 256, 0, stream>>>(W, h, cbuf);
    main_gemm<<<256, 512, 0, stream>>>(feat, wbuf, cbuf, v, psc);
    softmax_k<<<256, 256, 0, stream>>>(psc, out);
}

// Round 6
// 237.686 us; speedup vs baseline: 6.7936x; 1.0194x over previous
//
#include <hip/hip_runtime.h>
#include <hip/hip_fp16.h>

typedef _Float16 f16;
typedef _Float16 f16x8 __attribute__((ext_vector_type(8)));
typedef float f32x4 __attribute__((ext_vector_type(4)));

#define NCH 64         // chunks of 32 rows per batch
#define CHB 32768      // bytes per chunk (32 rows x 256 f32)
#define PSTRIDE 524288 // psc plane stride (floats) = 256*2048

// counted-vmcnt barrier: wait until <=N of this wave's VMEM ops outstanding,
// then workgroup barrier. Single asm => compiler can't reorder across it.
#define WAITB(N) asm volatile("s_waitcnt vmcnt(" #N ")\n\ts_barrier" ::: "memory")

// ---------------------------------------------------------------------------
// prep_w: W[0][d][k] (k<256, feature half) -> fp16 HI plane, MFMA B-frag order
// [ks(8)][ct(16)][lane(64)][j(8)]: ct=d>>4, lane=(d&15)|(((k>>3)&3)<<4),
// ks=k>>5, j=k&7. Frag (ks,ct) = contiguous 1 KiB.
// ---------------------------------------------------------------------------
__global__ void prep_w(const float* __restrict__ W, f16* __restrict__ wbuf) {
    int idx = blockIdx.x * 256 + threadIdx.x;   // 65536 total
    int d = idx >> 8, k = idx & 255;
    float w = W[d * 512 + k];
    int ct   = d >> 4;
    int lane = (d & 15) | (((k >> 3) & 3) << 4);
    int ks   = k >> 5;
    int j    = k & 7;
    wbuf[(((ks * 16 + ct) * 64) + lane) * 8 + j] = (f16)w;
}

// ---------------------------------------------------------------------------
// prep_c: c[b][d] = sum_e W[0][d][256+e] * h[b][e]   (fp32 exact, tiny)
// ---------------------------------------------------------------------------
__global__ void prep_c(const float* __restrict__ W, const float* __restrict__ h,
                       float* __restrict__ c) {
    __shared__ float hs[256];
    int b = blockIdx.x, d = threadIdx.x;
    hs[d] = h[b * 256 + d];
    __syncthreads();
    const float4* w4 = (const float4*)(W + d * 512 + 256);
    const float4* h4 = (const float4*)hs;
    float acc = 0.f;
#pragma unroll 8
    for (int e = 0; e < 64; ++e) {
        float4 a = w4[e], bb = h4[e];
        acc += a.x * bb.x + a.y * bb.y + a.z * bb.z + a.w * bb.w;
    }
    c[b * 256 + d] = acc;
}

// ---------------------------------------------------------------------------
// main_gemm: 32-row chunks, 4-slot LDS ring, depth-3 DMA prefetch with
// counted vmcnt (never drained to 0 in the loop). A staged raw fp32 via
// global_load_lds (linear dest; XOR swizzle folded into global source:
// L[x] = T[x ^ ((row&7)<<4)], row = x>>10). hi/lo fp16 split at LDS->reg;
// 2-pass split precision ahi*Whi + alo*Whi.
// 8 waves = 2 row-halves x 4 col-quarters; wave owns 16 rows x 64 cols.
// ---------------------------------------------------------------------------
__global__ __launch_bounds__(512, 2)
void main_gemm(const float* __restrict__ feat, const f16* __restrict__ wbuf,
               const float* __restrict__ cb, const float* __restrict__ vvec,
               float* __restrict__ psc) {
    __shared__ __align__(16) char lds[4 * CHB];   // 128 KiB ring

    const int tid = threadIdx.x;
    const int w = tid >> 6;       // wave 0..7
    const int l = tid & 63;
    const int g = l >> 4;         // 0..3
    const int lr = l & 15;
    const int wr = w >> 2;        // row-half 0/1
    const int wc = w & 3;         // col-quarter 0..3
    const int b = blockIdx.x;     // batch

    // ---- W-hi fragments for this wave's 64 cols: wf[ct][ks], 128 VGPRs ----
    f16x8 wf[4][8];
    {
        const f16x8* wp = (const f16x8*)wbuf;
#pragma unroll
        for (int ct = 0; ct < 4; ++ct) {
            int ctg = wc * 4 + ct;
#pragma unroll
            for (int ks = 0; ks < 8; ++ks)
                wf[ct][ks] = wp[(ks * 16 + ctg) * 64 + l];
        }
    }
    float c_[4], v_[4];
#pragma unroll
    for (int ct = 0; ct < 4; ++ct) {
        c_[ct] = cb[b * 256 + (wc * 4 + ct) * 16 + lr];
        v_[ct] = vvec[(wc * 4 + ct) * 16 + lr];
    }

    // DMA: thread j, iter i: LDS bytes [i*8192 + j*16) from global byte
    // i*8192 + sj*16; LDS row of offset x is x>>10 = i*8 + w, so the read-side
    // swizzle ((row&7)<<4) folds into the source as XOR of j's low 3 bits by w.
    const int sj = (tid & ~7) | ((tid ^ w) & 7);
    const char* tbb = (const char*)(feat + (size_t)b * 2048 * 256);

#define ISSUE(u)                                                                   \
    {                                                                              \
        const char* nb = tbb + (size_t)(u) * CHB;                                  \
        char* Q = lds + ((u) & 3) * CHB;                                           \
        _Pragma("unroll")                                                          \
        for (int i = 0; i < 4; ++i)                                                \
            __builtin_amdgcn_global_load_lds(                                      \
                (const __attribute__((address_space(1))) void*)(nb + i * 8192 + sj * 16), \
                (__attribute__((address_space(3))) void*)(Q + i * 8192 + tid * 16),\
                16, 0, 0);                                                         \
    }

    // ---- prologue: chunks 0,1,2 in flight (12 loads/wave) ----
    ISSUE(0); ISSUE(1); ISSUE(2);

    for (int t = 0; t < NCH; ++t) {
        // wait: chunk t's 4 loads done (12 -> 8 outstanding), sync all waves
        if (t <= NCH - 3) WAITB(8);
        else if (t == NCH - 2) WAITB(4);
        else WAITB(0);
        // slot (t+3)&3 == (t-1)&3: every wave passed the barrier => free
        if (t + 3 < NCH) ISSUE(t + 3);

        const char* P = lds + (t & 3) * CHB;
        f32x4 acc[4] = {};
#pragma unroll
        for (int ks = 0; ks < 8; ++ks) {
            int row  = wr * 16 + lr;
            int base = row * 1024 + ks * 128 + g * 32;
            int swz  = (row & 7) << 4;
            f32x4 r0 = *(const f32x4*)(P + (base ^ swz));
            f32x4 r1 = *(const f32x4*)(P + ((base + 16) ^ swz));
            f16x8 ahi, alo;
            ahi[0] = (f16)r0[0]; ahi[1] = (f16)r0[1];
            ahi[2] = (f16)r0[2]; ahi[3] = (f16)r0[3];
            ahi[4] = (f16)r1[0]; ahi[5] = (f16)r1[1];
            ahi[6] = (f16)r1[2]; ahi[7] = (f16)r1[3];
            alo[0] = (f16)(r0[0] - (float)ahi[0]);
            alo[1] = (f16)(r0[1] - (float)ahi[1]);
            alo[2] = (f16)(r0[2] - (float)ahi[2]);
            alo[3] = (f16)(r0[3] - (float)ahi[3]);
            alo[4] = (f16)(r1[0] - (float)ahi[4]);
            alo[5] = (f16)(r1[1] - (float)ahi[5]);
            alo[6] = (f16)(r1[2] - (float)ahi[6]);
            alo[7] = (f16)(r1[3] - (float)ahi[7]);
            acc[0] = __builtin_amdgcn_mfma_f32_16x16x32_f16(ahi, wf[0][ks], acc[0], 0, 0, 0);
            acc[1] = __builtin_amdgcn_mfma_f32_16x16x32_f16(ahi, wf[1][ks], acc[1], 0, 0, 0);
            acc[2] = __builtin_amdgcn_mfma_f32_16x16x32_f16(ahi, wf[2][ks], acc[2], 0, 0, 0);
            acc[3] = __builtin_amdgcn_mfma_f32_16x16x32_f16(ahi, wf[3][ks], acc[3], 0, 0, 0);
            acc[0] = __builtin_amdgcn_mfma_f32_16x16x32_f16(alo, wf[0][ks], acc[0], 0, 0, 0);
            acc[1] = __builtin_amdgcn_mfma_f32_16x16x32_f16(alo, wf[1][ks], acc[1], 0, 0, 0);
            acc[2] = __builtin_amdgcn_mfma_f32_16x16x32_f16(alo, wf[2][ks], acc[2], 0, 0, 0);
            acc[3] = __builtin_amdgcn_mfma_f32_16x16x32_f16(alo, wf[3][ks], acc[3], 0, 0, 0);
        }

        // ---- epilogue: +c, tanh, *v, reduce over 64 cols, one f32x4 store ---
        // acc[ct][r]: row = wr*16 + g*4 + r, col = (wc*4+ct)*16 + lr
        float s[4];
#pragma unroll
        for (int r = 0; r < 4; ++r) {
            float a = 0.f;
#pragma unroll
            for (int ct = 0; ct < 4; ++ct) {
                float x = acc[ct][r] + c_[ct];
                float tnh = 1.f - __fdividef(2.f, __expf(2.f * x) + 1.f);
                a += v_[ct] * tnh;
            }
            s[r] = a;
        }
#pragma unroll
        for (int m = 1; m < 16; m <<= 1) {
            s[0] += __shfl_xor(s[0], m, 64);
            s[1] += __shfl_xor(s[1], m, 64);
            s[2] += __shfl_xor(s[2], m, 64);
            s[3] += __shfl_xor(s[3], m, 64);
        }
        if (lr == 0) {
            size_t rowg = (size_t)b * 2048 + t * 32 + wr * 16 + g * 4;
            float4 o = {s[0], s[1], s[2], s[3]};
            *(float4*)(psc + (size_t)wc * PSTRIDE + rowg) = o;
        }
    }
#undef ISSUE
}

// ---------------------------------------------------------------------------
// softmax over n (2048) per b, summing 4 plane partials per row.
// ---------------------------------------------------------------------------
__global__ void softmax_k(const float* __restrict__ psc, float* __restrict__ out) {
    __shared__ float red[16];
    int b = blockIdx.x, tid = threadIdx.x;  // 256 threads
    float sc[8];
    float m = -3.4e38f;
#pragma unroll
    for (int q = 0; q < 8; ++q) {
        size_t row = (size_t)b * 2048 + q * 256 + tid;
        sc[q] = (psc[row] + psc[PSTRIDE + row]) +
                (psc[2 * PSTRIDE + row] + psc[3 * PSTRIDE + row]);
        m = fmaxf(m, sc[q]);
    }
#pragma unroll
    for (int d = 1; d < 64; d <<= 1) m = fmaxf(m, __shfl_xor(m, d, 64));
    if ((tid & 63) == 0) red[tid >> 6] = m;
    __syncthreads();
    m = fmaxf(fmaxf(red[0], red[1]), fmaxf(red[2], red[3]));
    float e[8], sum = 0.f;
#pragma unroll
    for (int q = 0; q < 8; ++q) { e[q] = __expf(sc[q] - m); sum += e[q]; }
#pragma unroll
    for (int d = 1; d < 64; d <<= 1) sum += __shfl_xor(sum, d, 64);
    if ((tid & 63) == 0) red[8 + (tid >> 6)] = sum;
    __syncthreads();
    sum = (red[8] + red[9]) + (red[10] + red[11]);
    float inv = __fdividef(1.f, sum);
#pragma unroll
    for (int q = 0; q < 8; ++q)
        out[(size_t)b * 2048 + q * 256 + tid] = e[q] * inv;
}

// ---------------------------------------------------------------------------
extern "C" void kernel_launch(void* const* d_in, const int* in_sizes, int n_in,
                              void* d_out, int out_size, void* d_ws, size_t ws_size,
                              hipStream_t stream) {
    const float* feat = (const float*)d_in[0];   // [256,2048,256]
    const float* h    = (const float*)d_in[1];   // [256,256]
    const float* v    = (const float*)d_in[2];   // [256]
    const float* W    = (const float*)d_in[3];   // [256,512]
    float* out = (float*)d_out;                  // [256,1,2048]

    f16*   wbuf = (f16*)d_ws;                         // 131072 B (hi plane)
    float* cbuf = (float*)((char*)d_ws + 131072);     // 262144 B
    float* psc  = (float*)((char*)d_ws + 524288);     // 4 planes x 2 MiB

    prep_w<<<256, 256, 0, stream>>>(W, wbuf);
    prep_c<<<256, 256, 0, stream>>>(W, h, cbuf);
    main_gemm<<<256, 512, 0, stream>>>(feat, wbuf, cbuf, v, psc);
    softmax_k<<<256, 256, 0, stream>>>(psc, out);
}